// Round 5
// baseline (199.965 us; speedup 1.0000x reference)
//
#include <hip/hip_runtime.h>
#include <float.h>
#include <math.h>

#define NN 1024
#define DD 64
#define CC 64
#define KK 20
#define EPSL 1e-3f

typedef __attribute__((ext_vector_type(8))) short short8;   // 8 bf16
typedef __attribute__((ext_vector_type(4))) float f32x4;    // MFMA acc

__device__ __forceinline__ unsigned short f2bf(float f) {   // RNE (cold paths)
    unsigned u = __float_as_uint(f);
    return (unsigned short)((u + 0x7fffu + ((u >> 16) & 1u)) >> 16);
}

// ---------------------------------------------------------------------------
// K2: exact bottom-20 set of a[j] = adj[row,j]*|f0[j]-f0[i]| per row, PLUS
// (first 49 blocks) the weight-prep formerly in k0:
//   b1t[n][k]: n<64: s1[n]*(W1a-W1b)[k][n] ; n>=64: s1[n-64]*W1b[k][n-64]
//   w2t[n][k] = bf16(w2[k][n]);  bb[c] = b1*s1 + be1 - mu1*s1
// f0 values are read straight from feats (column 0, stride-64 gathers, L2-hot).
// Top-k: T = 20th smallest of 64 lane-minima (u32 bitonic) -> candidates <=64
// -> compact (val<<32|idx) via LDS -> u32 bitonic on candidate values -> exact
// 20th value T* -> ballot/popcount emission (set semantics; mean over k is
// order-invariant). Wave-uniform exact fallback if candidates > 64.
// ---------------------------------------------------------------------------
__global__ __launch_bounds__(256) void k2_topk_prep(
        const float* __restrict__ adj, const float* __restrict__ feats,
        const float* __restrict__ w1, const float* __restrict__ w2,
        const float* __restrict__ b1, const float* __restrict__ g1,
        const float* __restrict__ be1, const float* __restrict__ mu1,
        const float* __restrict__ v1,
        unsigned short* __restrict__ b1t, unsigned short* __restrict__ w2t,
        float* __restrict__ bb, int* __restrict__ nnidx) {
    // ---- prep rider (blocks 0..48) ----
    int t = blockIdx.x * 256 + threadIdx.x;
    if (t < 8192) {
        int n = t >> 6, k = t & 63;
        float val;
        if (n < 64) {
            float s = g1[n] * rsqrtf(v1[n] + EPSL);
            val = (w1[k * CC + n] - w1[(k + DD) * CC + n]) * s;
        } else {
            int c = n - 64;
            float s = g1[c] * rsqrtf(v1[c] + EPSL);
            val = w1[(k + DD) * CC + c] * s;
        }
        b1t[t] = f2bf(val);
    } else if (t < 12288) {
        int i = t - 8192;
        int n = i >> 6, k = i & 63;
        w2t[i] = f2bf(w2[k * CC + n]);
    } else if (t < 12352) {
        int c = t - 12288;
        float s = g1[c] * rsqrtf(v1[c] + EPSL);
        bb[c] = b1[c] * s + be1[c] - mu1[c] * s;
    }

    // ---- top-k ----
    int lane = threadIdx.x & 63;
    int w    = threadIdx.x >> 6;
    int row  = blockIdx.x * 4 + w;
    int b    = row >> 10;
    __shared__ unsigned long long keybuf[4][64];
    const float4* arow = (const float4*)(adj + (size_t)row * NN);
    const float*  fB   = feats + (size_t)b * NN * DD;
    float f0i = feats[(size_t)row * DD];
    unsigned vu[16];
#pragma unroll
    for (int tv = 0; tv < 4; ++tv) {
        float4 av = arow[64 * tv + lane];
        int j0 = 256 * tv + 4 * lane;
        float fx = fB[(size_t)(j0 + 0) * DD];
        float fy = fB[(size_t)(j0 + 1) * DD];
        float fz = fB[(size_t)(j0 + 2) * DD];
        float fw = fB[(size_t)(j0 + 3) * DD];
        vu[tv * 4 + 0] = __float_as_uint(av.x * fabsf(fx - f0i));
        vu[tv * 4 + 1] = __float_as_uint(av.y * fabsf(fy - f0i));
        vu[tv * 4 + 2] = __float_as_uint(av.z * fabsf(fz - f0i));
        vu[tv * 4 + 3] = __float_as_uint(av.w * fabsf(fw - f0i));
    }
    unsigned x = vu[0];
#pragma unroll
    for (int tt = 1; tt < 16; ++tt) x = (vu[tt] < x) ? vu[tt] : x;
    // bitonic ascending sort of the 64 lane-minima (values only, u32)
#pragma unroll
    for (int k = 2; k <= 64; k <<= 1) {
#pragma unroll
        for (int j = k >> 1; j > 0; j >>= 1) {
            unsigned o = __shfl_xor(x, j);
            bool keepmin = (((lane & j) == 0) == ((lane & k) == 0));
            unsigned mn = (o < x) ? o : x;
            unsigned mx = (o < x) ? x : o;
            x = keepmin ? mn : mx;
        }
    }
    unsigned T = __shfl(x, 19);
    int cnt = 0;
#pragma unroll
    for (int tt = 0; tt < 16; ++tt) cnt += (vu[tt] <= T) ? 1 : 0;
    int inc = cnt;
#pragma unroll
    for (int off = 1; off < 64; off <<= 1) {
        int o = __shfl_up(inc, off);
        if (lane >= off) inc += o;
    }
    int total = __shfl(inc, 63);
    int* outp = nnidx + (size_t)row * KK;

    if (total <= 64) {
        int pos = inc - cnt;
#pragma unroll
        for (int tt = 0; tt < 16; ++tt) {
            if (vu[tt] <= T) {
                int j = 256 * (tt >> 2) + 4 * lane + (tt & 3);
                keybuf[w][pos] = ((unsigned long long)vu[tt] << 32) | (unsigned)j;
                pos++;
            }
        }
        unsigned long long key = (lane < total) ? keybuf[w][lane] : ~0ull;
        unsigned y = (unsigned)(key >> 32);
#pragma unroll
        for (int k = 2; k <= 64; k <<= 1) {
#pragma unroll
            for (int j = k >> 1; j > 0; j >>= 1) {
                unsigned o = __shfl_xor(y, j);
                bool keepmin = (((lane & j) == 0) == ((lane & k) == 0));
                unsigned mn = (o < y) ? o : y;
                unsigned mx = (o < y) ? y : o;
                y = keepmin ? mn : mx;
            }
        }
        unsigned Tstar = __shfl(y, 19);
        bool fl = (lane < total) && ((unsigned)(key >> 32) <= Tstar);
        unsigned long long msk = __ballot(fl);
        int p = __popcll(msk & ((1ull << lane) - 1ull));
        if (fl && p < KK) outp[p] = (int)(unsigned)key;
    } else {
        for (int r = 0; r < KK; ++r) {
            unsigned bv = vu[0];
            int bt = 0;
#pragma unroll
            for (int tt = 1; tt < 16; ++tt) {
                if (vu[tt] < bv) { bv = vu[tt]; bt = tt; }
            }
            int bj = 256 * (bt >> 2) + 4 * lane + (bt & 3);
            unsigned wv = bv;
            int wi = bj;
#pragma unroll
            for (int m = 1; m < 64; m <<= 1) {
                unsigned ov = __shfl_xor(wv, m);
                int oi = __shfl_xor(wi, m);
                if (ov < wv || (ov == wv && oi < wi)) { wv = ov; wi = oi; }
            }
            if (lane == 0) outp[r] = wi;
            if (((wi >> 2) & 63) == lane) {
                int s = ((wi >> 8) << 2) | (wi & 3);
#pragma unroll
                for (int tt = 0; tt < 16; ++tt) {
                    if (tt == s) vu[tt] = 0xFFFFFFFFu;
                }
            }
        }
    }
}

// ---------------------------------------------------------------------------
// K1: MFMA GEMM  [16384 x 64] @ [64 x 128] -> cterm | nterm (bf16, bn1-folded).
// Block = M=16 rows, 4 waves x N=32 cols -> 1024 blocks (4 blocks/CU).
// A = feats split bf16 (hi truncated + exact residual lo), dword-packed
// conversions (no RNE sequence in the hot path). 16 MFMAs/wave.
// ---------------------------------------------------------------------------
__global__ __launch_bounds__(256) void k1_mfma(
        const float* __restrict__ feats, const unsigned short* __restrict__ b1t,
        const float* __restrict__ bb,
        unsigned short* __restrict__ cterm, unsigned short* __restrict__ nterm) {
    int lane = threadIdx.x & 63, w = threadIdx.x >> 6;
    int col = lane & 15, quad = lane >> 4;
    int m0 = blockIdx.x * 16;
    int nb = w * 32;

    short8 bfr[2][2];
#pragma unroll
    for (int nt = 0; nt < 2; ++nt)
#pragma unroll
        for (int ks = 0; ks < 2; ++ks)
            bfr[nt][ks] = *(const short8*)(b1t + (nb + nt * 16 + col) * 64 + ks * 32 + quad * 8);

    float bbv[2] = {0.f, 0.f};
    if (w < 2) {
        bbv[0] = bb[nb + col];
        bbv[1] = bb[nb + 16 + col];
    }

    f32x4 acc[2];
    acc[0] = (f32x4)(0.f);
    acc[1] = (f32x4)(0.f);

    const float* fr = feats + (size_t)(m0 + col) * DD;
#pragma unroll
    for (int ks = 0; ks < 2; ++ks) {
        float4 p0 = *(const float4*)(fr + ks * 32 + quad * 8);
        float4 p1 = *(const float4*)(fr + ks * 32 + quad * 8 + 4);
        float f[8] = {p0.x, p0.y, p0.z, p0.w, p1.x, p1.y, p1.z, p1.w};
        uint4 hp, lp;
        unsigned hw[4], lw[4];
#pragma unroll
        for (int d = 0; d < 4; ++d) {
            float a = f[2 * d], bq = f[2 * d + 1];
            unsigned ua = __float_as_uint(a), ub = __float_as_uint(bq);
            unsigned am = ua & 0xffff0000u, bm = ub & 0xffff0000u;
            float ra = a - __uint_as_float(am);
            float rb = bq - __uint_as_float(bm);
            hw[d] = bm | (ua >> 16);
            lw[d] = (__float_as_uint(rb) & 0xffff0000u) | (__float_as_uint(ra) >> 16);
        }
        hp.x = hw[0]; hp.y = hw[1]; hp.z = hw[2]; hp.w = hw[3];
        lp.x = lw[0]; lp.y = lw[1]; lp.z = lw[2]; lp.w = lw[3];
        short8 ah = __builtin_bit_cast(short8, hp);
        short8 al = __builtin_bit_cast(short8, lp);
#pragma unroll
        for (int nt = 0; nt < 2; ++nt) {
            acc[nt] = __builtin_amdgcn_mfma_f32_16x16x32_bf16(ah, bfr[nt][ks], acc[nt], 0, 0, 0);
            acc[nt] = __builtin_amdgcn_mfma_f32_16x16x32_bf16(al, bfr[nt][ks], acc[nt], 0, 0, 0);
        }
    }

#pragma unroll
    for (int nt = 0; nt < 2; ++nt) {
        int n = nb + nt * 16 + col;
#pragma unroll
        for (int r = 0; r < 4; ++r) {
            int m = m0 + quad * 4 + r;
            unsigned short v = f2bf(acc[nt][r] + bbv[nt]);   // RNE at the store
            if (w < 2) cterm[(size_t)m * CC + n] = v;
            else       nterm[(size_t)m * CC + (n - 64)] = v;
        }
    }
}

// ---------------------------------------------------------------------------
// K3: LDS-free MFMA layer-2. One wave = 4 units (M=80), N=64, K=64.
// A-frag build works 2 bf16/dword: shl/and unpack, add, relu, and|shr pack
// (truncating round — <=1 ulp_bf16 bias, ~6e-4 on output). 40 MFMAs/wave.
// Epilogue: bn2+relu per C reg, static unit routing of quad-sums,
// shfl_xor(16,32) cross-quad reduce. Zero LDS.
// ---------------------------------------------------------------------------
__global__ __launch_bounds__(256, 3) void k3_mfma(
        const unsigned short* __restrict__ cterm, const unsigned short* __restrict__ nterm,
        const int* __restrict__ nnidx, const unsigned short* __restrict__ w2t,
        const float* __restrict__ b2,
        const float* __restrict__ g2, const float* __restrict__ be2,
        const float* __restrict__ mu2, const float* __restrict__ v2,
        float* __restrict__ out) {
    int lane = threadIdx.x & 63, w = threadIdx.x >> 6;
    int col = lane & 15, quad = lane >> 4;
    int wid = blockIdx.x * 4 + w;
    int u0 = wid * 4;
    int b  = u0 >> 10;

    short8 bfr[4][2];
#pragma unroll
    for (int nt = 0; nt < 4; ++nt)
#pragma unroll
        for (int ks = 0; ks < 2; ++ks)
            bfr[nt][ks] = *(const short8*)(w2t + (nt * 16 + col) * 64 + ks * 32 + quad * 8);

    float s2v[4], sh2v[4];
#pragma unroll
    for (int nt = 0; nt < 4; ++nt) {
        int c = nt * 16 + col;
        float s2 = g2[c] * rsqrtf(v2[c] + EPSL);
        s2v[nt]  = s2;
        sh2v[nt] = (b2[c] - mu2[c]) * s2 + be2[c];
    }

    f32x4 acc[5][4];
#pragma unroll
    for (int mt = 0; mt < 5; ++mt)
#pragma unroll
        for (int nt = 0; nt < 4; ++nt) acc[mt][nt] = (f32x4)(0.f);

    const int* ibase = nnidx + (size_t)u0 * KK;
    int jrow[5];
#pragma unroll
    for (int mt = 0; mt < 5; ++mt) jrow[mt] = ibase[mt * 16 + col];

#pragma unroll
    for (int mt = 0; mt < 5; ++mt) {
        int row = mt * 16 + col;             // 0..79
        int g   = (row * 205) >> 12;         // row / 20
        const unsigned short* np = nterm + (size_t)(b * NN + jrow[mt]) * CC;
        const unsigned short* cp = cterm + (size_t)(u0 + g) * CC;
        short8 afr[2];
#pragma unroll
        for (int ks = 0; ks < 2; ++ks) {
            int ch = ks * 32 + quad * 8;
            uint4 cv = *(const uint4*)(cp + ch);
            uint4 nv = *(const uint4*)(np + ch);
            unsigned cw[4] = {cv.x, cv.y, cv.z, cv.w};
            unsigned nw[4] = {nv.x, nv.y, nv.z, nv.w};
            uint4 rp;
            unsigned rw[4];
#pragma unroll
            for (int d = 0; d < 4; ++d) {
                float cl = __uint_as_float(cw[d] << 16);
                float chh = __uint_as_float(cw[d] & 0xffff0000u);
                float nl = __uint_as_float(nw[d] << 16);
                float nhh = __uint_as_float(nw[d] & 0xffff0000u);
                float sl = fmaxf(cl + nl, 0.f);
                float sh = fmaxf(chh + nhh, 0.f);
                rw[d] = (__float_as_uint(sh) & 0xffff0000u) | (__float_as_uint(sl) >> 16);
            }
            rp.x = rw[0]; rp.y = rw[1]; rp.z = rw[2]; rp.w = rw[3];
            afr[ks] = __builtin_bit_cast(short8, rp);
        }
#pragma unroll
        for (int ks = 0; ks < 2; ++ks)
#pragma unroll
            for (int nt = 0; nt < 4; ++nt)
                acc[mt][nt] = __builtin_amdgcn_mfma_f32_16x16x32_bf16(afr[ks], bfr[nt][ks], acc[mt][nt], 0, 0, 0);
    }

    // epilogue: bn2+relu, static unit routing, cross-quad butterfly
    float us0[4] = {0,0,0,0}, us1[4] = {0,0,0,0}, us2[4] = {0,0,0,0}, us3[4] = {0,0,0,0};
#pragma unroll
    for (int mt = 0; mt < 5; ++mt)
#pragma unroll
        for (int nt = 0; nt < 4; ++nt) {
            float qs = 0.f;
#pragma unroll
            for (int r = 0; r < 4; ++r)
                qs += fmaxf(acc[mt][nt][r] * s2v[nt] + sh2v[nt], 0.f);
            if (mt == 0) us0[nt] += qs;
            else if (mt == 4) us3[nt] += qs;
            else if (mt == 1) { float t = (quad >= 1) ? qs : 0.f; us1[nt] += t; us0[nt] += qs - t; }
            else if (mt == 2) { float t = (quad >= 2) ? qs : 0.f; us2[nt] += t; us1[nt] += qs - t; }
            else              { float t = (quad >= 3) ? qs : 0.f; us3[nt] += t; us2[nt] += qs - t; }
        }
#pragma unroll
    for (int nt = 0; nt < 4; ++nt) {
        us0[nt] += __shfl_xor(us0[nt], 16); us0[nt] += __shfl_xor(us0[nt], 32);
        us1[nt] += __shfl_xor(us1[nt], 16); us1[nt] += __shfl_xor(us1[nt], 32);
        us2[nt] += __shfl_xor(us2[nt], 16); us2[nt] += __shfl_xor(us2[nt], 32);
        us3[nt] += __shfl_xor(us3[nt], 16); us3[nt] += __shfl_xor(us3[nt], 32);
    }
#pragma unroll
    for (int nt = 0; nt < 4; ++nt) {
        float v = (quad == 0) ? us0[nt] : (quad == 1) ? us1[nt] : (quad == 2) ? us2[nt] : us3[nt];
        out[(size_t)(u0 + quad) * CC + nt * 16 + col] = v * 0.05f;
    }
}

// ---------------------------------------------------------------------------
extern "C" void kernel_launch(void* const* d_in, const int* in_sizes, int n_in,
                              void* d_out, int out_size, void* d_ws, size_t ws_size,
                              hipStream_t stream) {
    const float* feats = (const float*)d_in[0];
    const float* adj   = (const float*)d_in[1];
    const float* w1    = (const float*)d_in[2];
    const float* b1    = (const float*)d_in[3];
    const float* g1    = (const float*)d_in[4];
    const float* be1   = (const float*)d_in[5];
    const float* mu1   = (const float*)d_in[6];
    const float* v1    = (const float*)d_in[7];
    const float* w2    = (const float*)d_in[8];
    const float* b2    = (const float*)d_in[9];
    const float* g2    = (const float*)d_in[10];
    const float* be2   = (const float*)d_in[11];
    const float* mu2   = (const float*)d_in[12];
    const float* v2    = (const float*)d_in[13];
    float* out = (float*)d_out;

    char* ws = (char*)d_ws;
    unsigned short* cterm = (unsigned short*)(ws);                          // 2 MB
    unsigned short* nterm = (unsigned short*)(ws + 2u * 1024 * 1024);       // 2 MB
    int*            nnidx = (int*)  (ws + 4u * 1024 * 1024);                // 1.25 MB
    unsigned short* b1t   = (unsigned short*)(ws + 6u * 1024 * 1024);       // 16 KB
    unsigned short* w2t   = (unsigned short*)(ws + 6u * 1024 * 1024 + 16u * 1024); // 8 KB
    float*          bb    = (float*)(ws + 6u * 1024 * 1024 + 24u * 1024);   // 256 B

    // k2 carries the weight-prep in its first 49 blocks and precedes k1.
    k2_topk_prep<<<4096, 256, 0, stream>>>(adj, feats, w1, w2, b1,
                                           g1, be1, mu1, v1,
                                           b1t, w2t, bb, nnidx);
    k1_mfma<<<1024, 256, 0, stream>>>(feats, b1t, bb, cterm, nterm);
    k3_mfma<<<1024, 256, 0, stream>>>(cterm, nterm, nnidx, w2t, b2,
                                      g2, be2, mu2, v2, out);
}

// Round 6
// 146.956 us; speedup vs baseline: 1.3607x; 1.3607x over previous
//
#include <hip/hip_runtime.h>
#include <float.h>
#include <math.h>

#define NN 1024
#define DD 64
#define CC 64
#define KK 20
#define EPSL 1e-3f

typedef __attribute__((ext_vector_type(8))) short short8;   // 8 bf16
typedef __attribute__((ext_vector_type(4))) float f32x4;    // MFMA acc

__device__ __forceinline__ unsigned short f2bf(float f) {   // RNE (cold paths)
    unsigned u = __float_as_uint(f);
    return (unsigned short)((u + 0x7fffu + ((u >> 16) & 1u)) >> 16);
}

// ---------------------------------------------------------------------------
// K0: f0c[u] = feats[u][0]. The stride-64 column gather done ONCE (16384
// loads total) instead of per-wave in k2 (which was the R5 regression:
// 64-distinct-cacheline gathers serialized in the TA, 80 us).
// ---------------------------------------------------------------------------
__global__ __launch_bounds__(256) void k0_f0(const float* __restrict__ feats,
                                             float* __restrict__ f0c) {
    int u = blockIdx.x * 256 + threadIdx.x;
    f0c[u] = feats[(size_t)u * DD];
}

// ---------------------------------------------------------------------------
// K2: exact bottom-20 set of a[j] = adj[row,j]*|f0[j]-f0[i]| per row, PLUS
// (first 49 blocks) weight prep:
//   b1t[n][k]: n<64: s1[n]*(W1a-W1b)[k][n] ; n>=64: s1[n-64]*W1b[k][n-64]
//   w2t[n][k] = bf16(w2[k][n]);  bb[c] = b1*s1 + be1 - mu1*s1
// Top-k: T = 20th smallest of 64 lane-minima (u32 bitonic) -> candidates <=64
// -> compact (val<<32|idx) via LDS -> u32 bitonic on candidate values -> exact
// 20th value T* -> ballot/popcount emission (set semantics; mean over k is
// order-invariant). Wave-uniform exact fallback if candidates > 64.
// ---------------------------------------------------------------------------
__global__ __launch_bounds__(256) void k2_topk_prep(
        const float* __restrict__ adj, const float* __restrict__ f0c,
        const float* __restrict__ w1, const float* __restrict__ w2,
        const float* __restrict__ b1, const float* __restrict__ g1,
        const float* __restrict__ be1, const float* __restrict__ mu1,
        const float* __restrict__ v1,
        unsigned short* __restrict__ b1t, unsigned short* __restrict__ w2t,
        float* __restrict__ bb, int* __restrict__ nnidx) {
    // ---- prep rider (blocks 0..48) ----
    int t = blockIdx.x * 256 + threadIdx.x;
    if (t < 8192) {
        int n = t >> 6, k = t & 63;
        float val;
        if (n < 64) {
            float s = g1[n] * rsqrtf(v1[n] + EPSL);
            val = (w1[k * CC + n] - w1[(k + DD) * CC + n]) * s;
        } else {
            int c = n - 64;
            float s = g1[c] * rsqrtf(v1[c] + EPSL);
            val = w1[(k + DD) * CC + c] * s;
        }
        b1t[t] = f2bf(val);
    } else if (t < 12288) {
        int i = t - 8192;
        int n = i >> 6, k = i & 63;
        w2t[i] = f2bf(w2[k * CC + n]);
    } else if (t < 12352) {
        int c = t - 12288;
        float s = g1[c] * rsqrtf(v1[c] + EPSL);
        bb[c] = b1[c] * s + be1[c] - mu1[c] * s;
    }

    // ---- top-k ----
    int lane = threadIdx.x & 63;
    int w    = threadIdx.x >> 6;
    int row  = blockIdx.x * 4 + w;
    int b    = row >> 10;
    __shared__ unsigned long long keybuf[4][64];
    const float4* arow = (const float4*)(adj + (size_t)row * NN);
    const float4* frow = (const float4*)(f0c + (size_t)b * NN);
    float f0i = f0c[row];
    unsigned vu[16];
#pragma unroll
    for (int tv = 0; tv < 4; ++tv) {
        float4 av = arow[64 * tv + lane];
        float4 fv = frow[64 * tv + lane];
        vu[tv * 4 + 0] = __float_as_uint(av.x * fabsf(fv.x - f0i));
        vu[tv * 4 + 1] = __float_as_uint(av.y * fabsf(fv.y - f0i));
        vu[tv * 4 + 2] = __float_as_uint(av.z * fabsf(fv.z - f0i));
        vu[tv * 4 + 3] = __float_as_uint(av.w * fabsf(fv.w - f0i));
    }
    unsigned x = vu[0];
#pragma unroll
    for (int tt = 1; tt < 16; ++tt) x = (vu[tt] < x) ? vu[tt] : x;
    // bitonic ascending sort of the 64 lane-minima (values only, u32)
#pragma unroll
    for (int k = 2; k <= 64; k <<= 1) {
#pragma unroll
        for (int j = k >> 1; j > 0; j >>= 1) {
            unsigned o = __shfl_xor(x, j);
            bool keepmin = (((lane & j) == 0) == ((lane & k) == 0));
            unsigned mn = (o < x) ? o : x;
            unsigned mx = (o < x) ? x : o;
            x = keepmin ? mn : mx;
        }
    }
    unsigned T = __shfl(x, 19);
    int cnt = 0;
#pragma unroll
    for (int tt = 0; tt < 16; ++tt) cnt += (vu[tt] <= T) ? 1 : 0;
    int inc = cnt;
#pragma unroll
    for (int off = 1; off < 64; off <<= 1) {
        int o = __shfl_up(inc, off);
        if (lane >= off) inc += o;
    }
    int total = __shfl(inc, 63);
    int* outp = nnidx + (size_t)row * KK;

    if (total <= 64) {
        int pos = inc - cnt;
#pragma unroll
        for (int tt = 0; tt < 16; ++tt) {
            if (vu[tt] <= T) {
                int j = 256 * (tt >> 2) + 4 * lane + (tt & 3);
                keybuf[w][pos] = ((unsigned long long)vu[tt] << 32) | (unsigned)j;
                pos++;
            }
        }
        unsigned long long key = (lane < total) ? keybuf[w][lane] : ~0ull;
        unsigned y = (unsigned)(key >> 32);
#pragma unroll
        for (int k = 2; k <= 64; k <<= 1) {
#pragma unroll
            for (int j = k >> 1; j > 0; j >>= 1) {
                unsigned o = __shfl_xor(y, j);
                bool keepmin = (((lane & j) == 0) == ((lane & k) == 0));
                unsigned mn = (o < y) ? o : y;
                unsigned mx = (o < y) ? y : o;
                y = keepmin ? mn : mx;
            }
        }
        unsigned Tstar = __shfl(y, 19);
        bool fl = (lane < total) && ((unsigned)(key >> 32) <= Tstar);
        unsigned long long msk = __ballot(fl);
        int p = __popcll(msk & ((1ull << lane) - 1ull));
        if (fl && p < KK) outp[p] = (int)(unsigned)key;
    } else {
        for (int r = 0; r < KK; ++r) {
            unsigned bv = vu[0];
            int bt = 0;
#pragma unroll
            for (int tt = 1; tt < 16; ++tt) {
                if (vu[tt] < bv) { bv = vu[tt]; bt = tt; }
            }
            int bj = 256 * (bt >> 2) + 4 * lane + (bt & 3);
            unsigned wv = bv;
            int wi = bj;
#pragma unroll
            for (int m = 1; m < 64; m <<= 1) {
                unsigned ov = __shfl_xor(wv, m);
                int oi = __shfl_xor(wi, m);
                if (ov < wv || (ov == wv && oi < wi)) { wv = ov; wi = oi; }
            }
            if (lane == 0) outp[r] = wi;
            if (((wi >> 2) & 63) == lane) {
                int s = ((wi >> 8) << 2) | (wi & 3);
#pragma unroll
                for (int tt = 0; tt < 16; ++tt) {
                    if (tt == s) vu[tt] = 0xFFFFFFFFu;
                }
            }
        }
    }
}

// ---------------------------------------------------------------------------
// K1: MFMA GEMM  [16384 x 64] @ [64 x 128] -> cterm | nterm (bf16, bn1-folded).
// Block = M=16 rows, 4 waves x N=32 cols -> 1024 blocks (4 blocks/CU).
// A = feats split bf16 (hi truncated + exact residual lo), dword-packed
// conversions. 16 MFMAs/wave.
// ---------------------------------------------------------------------------
__global__ __launch_bounds__(256) void k1_mfma(
        const float* __restrict__ feats, const unsigned short* __restrict__ b1t,
        const float* __restrict__ bb,
        unsigned short* __restrict__ cterm, unsigned short* __restrict__ nterm) {
    int lane = threadIdx.x & 63, w = threadIdx.x >> 6;
    int col = lane & 15, quad = lane >> 4;
    int m0 = blockIdx.x * 16;
    int nb = w * 32;

    short8 bfr[2][2];
#pragma unroll
    for (int nt = 0; nt < 2; ++nt)
#pragma unroll
        for (int ks = 0; ks < 2; ++ks)
            bfr[nt][ks] = *(const short8*)(b1t + (nb + nt * 16 + col) * 64 + ks * 32 + quad * 8);

    float bbv[2] = {0.f, 0.f};
    if (w < 2) {
        bbv[0] = bb[nb + col];
        bbv[1] = bb[nb + 16 + col];
    }

    f32x4 acc[2];
    acc[0] = (f32x4)(0.f);
    acc[1] = (f32x4)(0.f);

    const float* fr = feats + (size_t)(m0 + col) * DD;
#pragma unroll
    for (int ks = 0; ks < 2; ++ks) {
        float4 p0 = *(const float4*)(fr + ks * 32 + quad * 8);
        float4 p1 = *(const float4*)(fr + ks * 32 + quad * 8 + 4);
        float f[8] = {p0.x, p0.y, p0.z, p0.w, p1.x, p1.y, p1.z, p1.w};
        uint4 hp, lp;
        unsigned hw[4], lw[4];
#pragma unroll
        for (int d = 0; d < 4; ++d) {
            float a = f[2 * d], bq = f[2 * d + 1];
            unsigned ua = __float_as_uint(a), ub = __float_as_uint(bq);
            unsigned am = ua & 0xffff0000u, bm = ub & 0xffff0000u;
            float ra = a - __uint_as_float(am);
            float rb = bq - __uint_as_float(bm);
            hw[d] = bm | (ua >> 16);
            lw[d] = (__float_as_uint(rb) & 0xffff0000u) | (__float_as_uint(ra) >> 16);
        }
        hp.x = hw[0]; hp.y = hw[1]; hp.z = hw[2]; hp.w = hw[3];
        lp.x = lw[0]; lp.y = lw[1]; lp.z = lw[2]; lp.w = lw[3];
        short8 ah = __builtin_bit_cast(short8, hp);
        short8 al = __builtin_bit_cast(short8, lp);
#pragma unroll
        for (int nt = 0; nt < 2; ++nt) {
            acc[nt] = __builtin_amdgcn_mfma_f32_16x16x32_bf16(ah, bfr[nt][ks], acc[nt], 0, 0, 0);
            acc[nt] = __builtin_amdgcn_mfma_f32_16x16x32_bf16(al, bfr[nt][ks], acc[nt], 0, 0, 0);
        }
    }

#pragma unroll
    for (int nt = 0; nt < 2; ++nt) {
        int n = nb + nt * 16 + col;
#pragma unroll
        for (int r = 0; r < 4; ++r) {
            int m = m0 + quad * 4 + r;
            unsigned short v = f2bf(acc[nt][r] + bbv[nt]);   // RNE at the store
            if (w < 2) cterm[(size_t)m * CC + n] = v;
            else       nterm[(size_t)m * CC + (n - 64)] = v;
        }
    }
}

// ---------------------------------------------------------------------------
// K3: LDS-free MFMA layer-2. One wave = 4 units (M=80), N=64, K=64.
// A-frag build works 2 bf16/dword: shl/and unpack, add, relu, and|shr pack
// (truncating round). 40 MFMAs/wave. Epilogue: bn2+relu per C reg, static
// unit routing of quad-sums, shfl_xor(16,32) cross-quad reduce. Zero LDS.
// ---------------------------------------------------------------------------
__global__ __launch_bounds__(256, 3) void k3_mfma(
        const unsigned short* __restrict__ cterm, const unsigned short* __restrict__ nterm,
        const int* __restrict__ nnidx, const unsigned short* __restrict__ w2t,
        const float* __restrict__ b2,
        const float* __restrict__ g2, const float* __restrict__ be2,
        const float* __restrict__ mu2, const float* __restrict__ v2,
        float* __restrict__ out) {
    int lane = threadIdx.x & 63, w = threadIdx.x >> 6;
    int col = lane & 15, quad = lane >> 4;
    int wid = blockIdx.x * 4 + w;
    int u0 = wid * 4;
    int b  = u0 >> 10;

    short8 bfr[4][2];
#pragma unroll
    for (int nt = 0; nt < 4; ++nt)
#pragma unroll
        for (int ks = 0; ks < 2; ++ks)
            bfr[nt][ks] = *(const short8*)(w2t + (nt * 16 + col) * 64 + ks * 32 + quad * 8);

    float s2v[4], sh2v[4];
#pragma unroll
    for (int nt = 0; nt < 4; ++nt) {
        int c = nt * 16 + col;
        float s2 = g2[c] * rsqrtf(v2[c] + EPSL);
        s2v[nt]  = s2;
        sh2v[nt] = (b2[c] - mu2[c]) * s2 + be2[c];
    }

    f32x4 acc[5][4];
#pragma unroll
    for (int mt = 0; mt < 5; ++mt)
#pragma unroll
        for (int nt = 0; nt < 4; ++nt) acc[mt][nt] = (f32x4)(0.f);

    const int* ibase = nnidx + (size_t)u0 * KK;
    int jrow[5];
#pragma unroll
    for (int mt = 0; mt < 5; ++mt) jrow[mt] = ibase[mt * 16 + col];

#pragma unroll
    for (int mt = 0; mt < 5; ++mt) {
        int row = mt * 16 + col;             // 0..79
        int g   = (row * 205) >> 12;         // row / 20
        const unsigned short* np = nterm + (size_t)(b * NN + jrow[mt]) * CC;
        const unsigned short* cp = cterm + (size_t)(u0 + g) * CC;
        short8 afr[2];
#pragma unroll
        for (int ks = 0; ks < 2; ++ks) {
            int ch = ks * 32 + quad * 8;
            uint4 cv = *(const uint4*)(cp + ch);
            uint4 nv = *(const uint4*)(np + ch);
            unsigned cw[4] = {cv.x, cv.y, cv.z, cv.w};
            unsigned nw[4] = {nv.x, nv.y, nv.z, nv.w};
            uint4 rp;
            unsigned rw[4];
#pragma unroll
            for (int d = 0; d < 4; ++d) {
                float cl  = __uint_as_float(cw[d] << 16);
                float chh = __uint_as_float(cw[d] & 0xffff0000u);
                float nl  = __uint_as_float(nw[d] << 16);
                float nhh = __uint_as_float(nw[d] & 0xffff0000u);
                float sl = fmaxf(cl + nl, 0.f);
                float sh = fmaxf(chh + nhh, 0.f);
                rw[d] = (__float_as_uint(sh) & 0xffff0000u) | (__float_as_uint(sl) >> 16);
            }
            rp.x = rw[0]; rp.y = rw[1]; rp.z = rw[2]; rp.w = rw[3];
            afr[ks] = __builtin_bit_cast(short8, rp);
        }
#pragma unroll
        for (int ks = 0; ks < 2; ++ks)
#pragma unroll
            for (int nt = 0; nt < 4; ++nt)
                acc[mt][nt] = __builtin_amdgcn_mfma_f32_16x16x32_bf16(afr[ks], bfr[nt][ks], acc[mt][nt], 0, 0, 0);
    }

    // epilogue: bn2+relu, static unit routing, cross-quad butterfly
    float us0[4] = {0,0,0,0}, us1[4] = {0,0,0,0}, us2[4] = {0,0,0,0}, us3[4] = {0,0,0,0};
#pragma unroll
    for (int mt = 0; mt < 5; ++mt)
#pragma unroll
        for (int nt = 0; nt < 4; ++nt) {
            float qs = 0.f;
#pragma unroll
            for (int r = 0; r < 4; ++r)
                qs += fmaxf(acc[mt][nt][r] * s2v[nt] + sh2v[nt], 0.f);
            if (mt == 0) us0[nt] += qs;
            else if (mt == 4) us3[nt] += qs;
            else if (mt == 1) { float t = (quad >= 1) ? qs : 0.f; us1[nt] += t; us0[nt] += qs - t; }
            else if (mt == 2) { float t = (quad >= 2) ? qs : 0.f; us2[nt] += t; us1[nt] += qs - t; }
            else              { float t = (quad >= 3) ? qs : 0.f; us3[nt] += t; us2[nt] += qs - t; }
        }
#pragma unroll
    for (int nt = 0; nt < 4; ++nt) {
        us0[nt] += __shfl_xor(us0[nt], 16); us0[nt] += __shfl_xor(us0[nt], 32);
        us1[nt] += __shfl_xor(us1[nt], 16); us1[nt] += __shfl_xor(us1[nt], 32);
        us2[nt] += __shfl_xor(us2[nt], 16); us2[nt] += __shfl_xor(us2[nt], 32);
        us3[nt] += __shfl_xor(us3[nt], 16); us3[nt] += __shfl_xor(us3[nt], 32);
    }
#pragma unroll
    for (int nt = 0; nt < 4; ++nt) {
        float v = (quad == 0) ? us0[nt] : (quad == 1) ? us1[nt] : (quad == 2) ? us2[nt] : us3[nt];
        out[(size_t)(u0 + quad) * CC + nt * 16 + col] = v * 0.05f;
    }
}

// ---------------------------------------------------------------------------
extern "C" void kernel_launch(void* const* d_in, const int* in_sizes, int n_in,
                              void* d_out, int out_size, void* d_ws, size_t ws_size,
                              hipStream_t stream) {
    const float* feats = (const float*)d_in[0];
    const float* adj   = (const float*)d_in[1];
    const float* w1    = (const float*)d_in[2];
    const float* b1    = (const float*)d_in[3];
    const float* g1    = (const float*)d_in[4];
    const float* be1   = (const float*)d_in[5];
    const float* mu1   = (const float*)d_in[6];
    const float* v1    = (const float*)d_in[7];
    const float* w2    = (const float*)d_in[8];
    const float* b2    = (const float*)d_in[9];
    const float* g2    = (const float*)d_in[10];
    const float* be2   = (const float*)d_in[11];
    const float* mu2   = (const float*)d_in[12];
    const float* v2    = (const float*)d_in[13];
    float* out = (float*)d_out;

    char* ws = (char*)d_ws;
    unsigned short* cterm = (unsigned short*)(ws);                          // 2 MB
    unsigned short* nterm = (unsigned short*)(ws + 2u * 1024 * 1024);       // 2 MB
    int*            nnidx = (int*)  (ws + 4u * 1024 * 1024);                // 1.25 MB
    unsigned short* b1t   = (unsigned short*)(ws + 6u * 1024 * 1024);       // 16 KB
    unsigned short* w2t   = (unsigned short*)(ws + 6u * 1024 * 1024 + 16u * 1024); // 8 KB
    float*          bb    = (float*)(ws + 6u * 1024 * 1024 + 24u * 1024);   // 256 B
    float*          f0c   = (float*)(ws + 6u * 1024 * 1024 + 32u * 1024);   // 64 KB

    k0_f0<<<64, 256, 0, stream>>>(feats, f0c);
    k2_topk_prep<<<4096, 256, 0, stream>>>(adj, f0c, w1, w2, b1,
                                           g1, be1, mu1, v1,
                                           b1t, w2t, bb, nnidx);
    k1_mfma<<<1024, 256, 0, stream>>>(feats, b1t, bb, cterm, nterm);
    k3_mfma<<<1024, 256, 0, stream>>>(cterm, nterm, nnidx, w2t, b2,
                                      g2, be2, mu2, v2, out);
}